// Round 11
// baseline (1069.509 us; speedup 1.0000x reference)
//
#include <hip/hip_runtime.h>
#include <cmath>

#define FIXCAP  262144u   // elist1 cap (2 MiB)
#define FIXCAP2 131072u   // elist2 cap (1 MiB)
#define ROWCAP 32768u

// Decision-boundary protection bands — re-tuned for BOTH GEMMs on bf16-split
// MFMA.  z2 fast-path error sigma ~6.4e-6 (gemm1 h1 err 5e-6 + gemm2 4e-6);
// tier-1 (fix_near, fp64 dot of STORED h1) inherits h1's ~5e-6 error so its
// escalation band B2 must cover it; exact backstops (fix_full, row_exact)
// recompute h1 from F in fp64 and are immune.
#define B03  4e-5f        // g vs 0.3            -> element fix (tier 1)
#define B01  4e-5f        // |comp| vs 0.1       -> element fix (tier 1)
#define B2   2e-5         // tier-1 residual band -> tier-2 full fp64 fix
#define BDYN 5e-5f        // |dyn| vs thr        -> row fp64 redo (row_exact)

typedef __attribute__((ext_vector_type(8))) short bf16x8;     // 8 bf16 = 4 VGPR
typedef __attribute__((ext_vector_type(8))) unsigned short ushort8;
typedef __attribute__((ext_vector_type(4))) float f32x4;

__device__ __forceinline__ unsigned short bf16_rne(float x)
{
    unsigned u = __float_as_uint(x);
    unsigned r = u + 0x7FFFu + ((u >> 16) & 1u);
    return (unsigned short)(r >> 16);
}
__device__ __forceinline__ float bf16_to_f(unsigned short h)
{
    return __uint_as_float(((unsigned)h) << 16);
}

// ---------------------------------------------------------------------------
// split_wg1: wg1 [1024 k][256 n] fp32 -> wg1T_h/_l bf16 [256 n][1024 k].
// ---------------------------------------------------------------------------
__global__ __launch_bounds__(256) void split_wg1(
    const float* __restrict__ wg1, unsigned short* __restrict__ th,
    unsigned short* __restrict__ tl)
{
    const int n = blockIdx.x;      // 256
    #pragma unroll
    for (int kc = 0; kc < 4; ++kc) {
        const int k = kc * 256 + threadIdx.x;
        float x = wg1[(size_t)k * 256 + n];
        unsigned short h = bf16_rne(x);
        th[(size_t)n * 1024 + k] = h;
        tl[(size_t)n * 1024 + k] = bf16_rne(x - bf16_to_f(h));
    }
}

// ---------------------------------------------------------------------------
// split_wg2: wg2 [256 k][1024 n] fp32 -> wg2T_h/_l bf16 [1024 n][256 k].
// ---------------------------------------------------------------------------
__global__ __launch_bounds__(256) void split_wg2(
    const float* __restrict__ wg2, unsigned short* __restrict__ th,
    unsigned short* __restrict__ tl)
{
    const int n = blockIdx.x;      // 1024
    const int k = threadIdx.x;     // 256
    float x = wg2[(size_t)k * 1024 + n];
    unsigned short h = bf16_rne(x);
    th[(size_t)n * 256 + k] = h;
    tl[(size_t)n * 256 + k] = bf16_rne(x - bf16_to_f(h));
}

// ---------------------------------------------------------------------------
// K1 (MFMA): h1 = relu(F @ Wg1 + b1) via bf16 split-2 (same validated
// machinery as gemm2_mfma).  Block 128x128, 4 waves 2x2, K-step 32, K=1024.
// A = F (fp32, split during staging); B = pre-split wg1T.  Output fp32 h1.
// ---------------------------------------------------------------------------
__global__ __launch_bounds__(256) void gemm1_mfma(
    const float* __restrict__ F, const unsigned short* __restrict__ bTh,
    const unsigned short* __restrict__ bTl, const float* __restrict__ bias,
    float* __restrict__ out, int M)
{
    __shared__ __align__(16) unsigned short Ah[128][40];
    __shared__ __align__(16) unsigned short Al[128][40];
    __shared__ __align__(16) unsigned short Bh[128][40];
    __shared__ __align__(16) unsigned short Bl[128][40];

    const int tid  = threadIdx.x;
    const int lane = tid & 63;
    const int wave = tid >> 6;
    const int wr = wave >> 1, wc = wave & 1;
    const int bm = blockIdx.x * 128;
    const int bn = blockIdx.y * 128;

    f32x4 acc[4][4];
    #pragma unroll
    for (int mi = 0; mi < 4; ++mi)
        #pragma unroll
        for (int ni = 0; ni < 4; ++ni)
            acc[mi][ni] = (f32x4){0.f, 0.f, 0.f, 0.f};

    const int sr = tid >> 1;          // staging row 0..127
    const int sh = tid & 1;           // 16-wide k chunk

    for (int k0 = 0; k0 < 1024; k0 += 32) {
        __syncthreads();
        // stage A: F fp32 -> split bf16
        {
            const float* src = F + (size_t)(bm + sr) * 1024 + k0 + sh * 16;
            unsigned short* dh = &Ah[sr][sh * 16];
            unsigned short* dl = &Al[sr][sh * 16];
            #pragma unroll
            for (int i = 0; i < 2; ++i) {
                float4 f0 = ((const float4*)src)[2 * i + 0];
                float4 f1 = ((const float4*)src)[2 * i + 1];
                float xs[8] = {f0.x, f0.y, f0.z, f0.w, f1.x, f1.y, f1.z, f1.w};
                ushort8 vh, vl;
                #pragma unroll
                for (int j = 0; j < 8; ++j) {
                    unsigned short hh = bf16_rne(xs[j]);
                    vh[j] = hh;
                    vl[j] = bf16_rne(xs[j] - bf16_to_f(hh));
                }
                ((ushort8*)dh)[i] = vh;
                ((ushort8*)dl)[i] = vl;
            }
        }
        // stage B: pre-split bf16 copies
        {
            const ushort8* s0 = (const ushort8*)(bTh + (size_t)(bn + sr) * 1024 + k0 + sh * 16);
            const ushort8* s1 = (const ushort8*)(bTl + (size_t)(bn + sr) * 1024 + k0 + sh * 16);
            ushort8* d0 = (ushort8*)&Bh[sr][sh * 16];
            ushort8* d1 = (ushort8*)&Bl[sr][sh * 16];
            d0[0] = s0[0]; d0[1] = s0[1];
            d1[0] = s1[0]; d1[1] = s1[1];
        }
        __syncthreads();

        const int ko = (lane >> 4) * 8;
        const int fr = lane & 15;
        bf16x8 ah[4], al[4], bh[4], bl[4];
        #pragma unroll
        for (int mi = 0; mi < 4; ++mi) {
            ah[mi] = *(const bf16x8*)&Ah[wr * 64 + mi * 16 + fr][ko];
            al[mi] = *(const bf16x8*)&Al[wr * 64 + mi * 16 + fr][ko];
        }
        #pragma unroll
        for (int ni = 0; ni < 4; ++ni) {
            bh[ni] = *(const bf16x8*)&Bh[wc * 64 + ni * 16 + fr][ko];
            bl[ni] = *(const bf16x8*)&Bl[wc * 64 + ni * 16 + fr][ko];
        }
        #pragma unroll
        for (int mi = 0; mi < 4; ++mi) {
            #pragma unroll
            for (int ni = 0; ni < 4; ++ni) {
                acc[mi][ni] = __builtin_amdgcn_mfma_f32_16x16x32_bf16(ah[mi], bh[ni], acc[mi][ni], 0, 0, 0);
                acc[mi][ni] = __builtin_amdgcn_mfma_f32_16x16x32_bf16(ah[mi], bl[ni], acc[mi][ni], 0, 0, 0);
                acc[mi][ni] = __builtin_amdgcn_mfma_f32_16x16x32_bf16(al[mi], bh[ni], acc[mi][ni], 0, 0, 0);
            }
        }
    }

    // epilogue: relu(acc + bias) -> h1 fp32
    #pragma unroll
    for (int ni = 0; ni < 4; ++ni) {
        const int col = bn + wc * 64 + ni * 16 + (lane & 15);
        const float bi = bias[col];
        #pragma unroll
        for (int mi = 0; mi < 4; ++mi) {
            #pragma unroll
            for (int r = 0; r < 4; ++r) {
                const int row = bm + wr * 64 + mi * 16 + (lane >> 4) * 4 + r;
                out[(size_t)row * 256 + col] = fmaxf(acc[mi][ni][r] + bi, 0.f);
            }
        }
    }
}

// ---------------------------------------------------------------------------
// K2 (MFMA): z2 = h1 @ Wg2 + b2 — UNCHANGED from validated round 10.
// ---------------------------------------------------------------------------
__global__ __launch_bounds__(256) void gemm2_mfma(
    const float* __restrict__ h1, const unsigned short* __restrict__ bTh,
    const unsigned short* __restrict__ bTl, const float* __restrict__ bias,
    const float* __restrict__ F, float* __restrict__ out,
    unsigned* __restrict__ ectr1, uint2* __restrict__ elist1, int M)
{
    __shared__ __align__(16) unsigned short Ah[128][40];
    __shared__ __align__(16) unsigned short Al[128][40];
    __shared__ __align__(16) unsigned short Bh[128][40];
    __shared__ __align__(16) unsigned short Bl[128][40];

    const int tid  = threadIdx.x;
    const int lane = tid & 63;
    const int wave = tid >> 6;
    const int wr = wave >> 1, wc = wave & 1;
    const int bm = blockIdx.x * 128;
    const int bn = blockIdx.y * 128;

    f32x4 acc[4][4];
    #pragma unroll
    for (int mi = 0; mi < 4; ++mi)
        #pragma unroll
        for (int ni = 0; ni < 4; ++ni)
            acc[mi][ni] = (f32x4){0.f, 0.f, 0.f, 0.f};

    const int sr = tid >> 1;
    const int sh = tid & 1;

    for (int k0 = 0; k0 < 256; k0 += 32) {
        __syncthreads();
        // stage A: h1 fp32 -> split bf16
        {
            const float* src = h1 + (size_t)(bm + sr) * 256 + k0 + sh * 16;
            unsigned short* dh = &Ah[sr][sh * 16];
            unsigned short* dl = &Al[sr][sh * 16];
            #pragma unroll
            for (int i = 0; i < 2; ++i) {
                float4 f0 = ((const float4*)src)[2 * i + 0];
                float4 f1 = ((const float4*)src)[2 * i + 1];
                float xs[8] = {f0.x, f0.y, f0.z, f0.w, f1.x, f1.y, f1.z, f1.w};
                ushort8 vh, vl;
                #pragma unroll
                for (int j = 0; j < 8; ++j) {
                    unsigned short hh = bf16_rne(xs[j]);
                    vh[j] = hh;
                    vl[j] = bf16_rne(xs[j] - bf16_to_f(hh));
                }
                ((ushort8*)dh)[i] = vh;
                ((ushort8*)dl)[i] = vl;
            }
        }
        // stage B: pre-split bf16 copies
        {
            const ushort8* s0 = (const ushort8*)(bTh + (size_t)(bn + sr) * 256 + k0 + sh * 16);
            const ushort8* s1 = (const ushort8*)(bTl + (size_t)(bn + sr) * 256 + k0 + sh * 16);
            ushort8* d0 = (ushort8*)&Bh[sr][sh * 16];
            ushort8* d1 = (ushort8*)&Bl[sr][sh * 16];
            d0[0] = s0[0]; d0[1] = s0[1];
            d1[0] = s1[0]; d1[1] = s1[1];
        }
        __syncthreads();

        const int ko = (lane >> 4) * 8;
        const int fr = lane & 15;
        bf16x8 ah[4], al[4], bh[4], bl[4];
        #pragma unroll
        for (int mi = 0; mi < 4; ++mi) {
            ah[mi] = *(const bf16x8*)&Ah[wr * 64 + mi * 16 + fr][ko];
            al[mi] = *(const bf16x8*)&Al[wr * 64 + mi * 16 + fr][ko];
        }
        #pragma unroll
        for (int ni = 0; ni < 4; ++ni) {
            bh[ni] = *(const bf16x8*)&Bh[wc * 64 + ni * 16 + fr][ko];
            bl[ni] = *(const bf16x8*)&Bl[wc * 64 + ni * 16 + fr][ko];
        }
        #pragma unroll
        for (int mi = 0; mi < 4; ++mi) {
            #pragma unroll
            for (int ni = 0; ni < 4; ++ni) {
                acc[mi][ni] = __builtin_amdgcn_mfma_f32_16x16x32_bf16(ah[mi], bh[ni], acc[mi][ni], 0, 0, 0);
                acc[mi][ni] = __builtin_amdgcn_mfma_f32_16x16x32_bf16(ah[mi], bl[ni], acc[mi][ni], 0, 0, 0);
                acc[mi][ni] = __builtin_amdgcn_mfma_f32_16x16x32_bf16(al[mi], bh[ni], acc[mi][ni], 0, 0, 0);
            }
        }
    }

    // epilogue: sigmoid gate + threshold + band flags (fp32 fast path)
    #pragma unroll
    for (int ni = 0; ni < 4; ++ni) {
        const int col = bn + wc * 64 + ni * 16 + (lane & 15);
        const float bi = bias[col];
        #pragma unroll
        for (int mi = 0; mi < 4; ++mi) {
            #pragma unroll
            for (int r = 0; r < 4; ++r) {
                const int row = bm + wr * 64 + mi * 16 + (lane >> 4) * 4 + r;
                float z = acc[mi][ni][r] + bi;
                float gw = 1.0f / (1.0f + __expf(-z));
                float g = F[(size_t)row * 1024 + col] * gw;
                float c = (g > 0.3f) ? 0.f : g;
                if (fabsf(g - 0.3f) < B03 || fabsf(fabsf(c) - 0.1f) < B01) {
                    unsigned idx = atomicAdd(ectr1, 1u);
                    if (idx < FIXCAP) elist1[idx] = make_uint2((unsigned)row, (unsigned)col);
                }
                out[(size_t)row * 1024 + col] = c;
            }
        }
    }
}

// ---------------------------------------------------------------------------
// fix_near (tier 1): fp64 dot of STORED h1 with Wg2 column.  Escalation band
// B2 widened to cover h1's MFMA-split error (~5e-6 sigma in z2).
// ---------------------------------------------------------------------------
__global__ __launch_bounds__(256) void fix_near(
    const float* __restrict__ h1, const float* __restrict__ F,
    const float* __restrict__ Wg2, const float* __restrict__ bg2,
    const unsigned* __restrict__ ectr1, const uint2* __restrict__ elist1,
    unsigned* __restrict__ ectr2, uint2* __restrict__ elist2,
    float* __restrict__ out, int* __restrict__ corr)
{
    __shared__ double red[4];
    const int tid = threadIdx.x;
    unsigned cnt = *ectr1;
    if (cnt > FIXCAP) cnt = FIXCAP;

    for (unsigned e = blockIdx.x; e < cnt; e += gridDim.x) {
        const unsigned row = elist1[e].x, col = elist1[e].y;
        double p = (double)h1[(size_t)row * 256 + tid]
                 * (double)Wg2[(size_t)tid * 1024 + col];
        #pragma unroll
        for (int o = 32; o > 0; o >>= 1) p += __shfl_down(p, o, 64);
        if ((tid & 63) == 0) red[tid >> 6] = p;
        __syncthreads();
        if (tid == 0) {
            double z2 = red[0] + red[1] + red[2] + red[3] + (double)bg2[col];
            double gw = 1.0 / (1.0 + exp(-z2));
            double g = (double)F[(size_t)row * 1024 + col] * gw;
            double c = (g > 0.3) ? 0.0 : g;
            bool near = (fabs(g - 0.3) < B2) || (fabs(fabs(c) - 0.1) < B2);
            if (near) {
                unsigned i2 = atomicAdd(ectr2, 1u);
                if (i2 < FIXCAP2) elist2[i2] = make_uint2(row, col);
            } else {
                float cf = (float)c;
                int d_ref = (fabs(c) < 0.1) ? 1 : 0;
                int d_st  = (fabsf(cf) < 0.1f) ? 1 : 0;
                if (d_ref != d_st) atomicAdd(&corr[row], d_ref - d_st);
                out[(size_t)row * 1024 + col] = cf;
            }
        }
        __syncthreads();
    }
}

// ---------------------------------------------------------------------------
// dbuf 16KB weight-tile pipeline pieces (validated round 8).
// ---------------------------------------------------------------------------
#define WT_PREFETCH(ptr)                                                        \
            r0 = *(const float4*)((ptr) + 0 * 1024 + tid * 4);                  \
            r1 = *(const float4*)((ptr) + 1 * 1024 + tid * 4);                  \
            r2 = *(const float4*)((ptr) + 2 * 1024 + tid * 4);                  \
            r3 = *(const float4*)((ptr) + 3 * 1024 + tid * 4);

#define WT_STORE(B)                                                             \
            *(float4*)&Wt[B][0 * 1024 + tid * 4] = r0;                          \
            *(float4*)&Wt[B][1 * 1024 + tid * 4] = r1;                          \
            *(float4*)&Wt[B][2 * 1024 + tid * 4] = r2;                          \
            *(float4*)&Wt[B][3 * 1024 + tid * 4] = r3;

// ---------------------------------------------------------------------------
// fix_full (tier 2): true fp64 recompute from F — UNCHANGED (validated r8),
// immune to gemm1's MFMA error.
// ---------------------------------------------------------------------------
__global__ __launch_bounds__(256) void fix_full(
    const float* __restrict__ F, const float* __restrict__ Wg1,
    const float* __restrict__ bg1, const float* __restrict__ Wg2,
    const float* __restrict__ bg2,
    const unsigned* __restrict__ ectr2, const uint2* __restrict__ elist2,
    float* __restrict__ out, int* __restrict__ corr)
{
    __shared__ float Fs[1024];
    __shared__ float Wt[2][4096];
    __shared__ double red[4];
    const int tid = threadIdx.x;
    unsigned cnt = *ectr2;
    if (cnt > FIXCAP2) cnt = FIXCAP2;

    for (unsigned e = blockIdx.x; e < cnt; e += gridDim.x) {
        const unsigned row = elist2[e].x, col = elist2[e].y;
        __syncthreads();
        *(float4*)&Fs[tid * 4] = *(const float4*)(F + (size_t)row * 1024 + tid * 4);

        float4 r0, r1, r2, r3;
        WT_PREFETCH(Wg1)
        WT_STORE(0)
        __syncthreads();
        double p0 = 0.0, p1 = 0.0, p2 = 0.0, p3 = 0.0;
        int buf = 0;
        for (int t = 0; t < 64; ++t) {
            if (t + 1 < 64) { const float* np = Wg1 + (size_t)(t + 1) * 4096; WT_PREFETCH(np) }
            const int kb = t * 16;
            #pragma unroll
            for (int kk = 0; kk < 16; kk += 4) {
                p0 += (double)Fs[kb + kk + 0] * (double)Wt[buf][(kk + 0) * 256 + tid];
                p1 += (double)Fs[kb + kk + 1] * (double)Wt[buf][(kk + 1) * 256 + tid];
                p2 += (double)Fs[kb + kk + 2] * (double)Wt[buf][(kk + 2) * 256 + tid];
                p3 += (double)Fs[kb + kk + 3] * (double)Wt[buf][(kk + 3) * 256 + tid];
            }
            if (t + 1 < 64) {
                const int nb = buf ^ 1;
                WT_STORE(nb)
                __syncthreads();
                buf = nb;
            }
        }
        double h = ((p0 + p1) + (p2 + p3)) + (double)bg1[tid];
        h = (h > 0.0) ? h : 0.0;
        double p = h * (double)Wg2[(size_t)tid * 1024 + col];
        #pragma unroll
        for (int o = 32; o > 0; o >>= 1) p += __shfl_down(p, o, 64);
        if ((tid & 63) == 0) red[tid >> 6] = p;
        __syncthreads();
        if (tid == 0) {
            double z2 = red[0] + red[1] + red[2] + red[3] + (double)bg2[col];
            double gw = 1.0 / (1.0 + exp(-z2));
            double g = (double)Fs[col] * gw;
            double c = (g > 0.3) ? 0.0 : g;
            float cf = (float)c;
            int d_ref = (fabs(c) < 0.1) ? 1 : 0;
            int d_st  = (fabsf(cf) < 0.1f) ? 1 : 0;
            if (d_ref != d_st) atomicAdd(&corr[row], d_ref - d_st);
            out[(size_t)row * 1024 + col] = cf;
        }
    }
}

// ---------------------------------------------------------------------------
// K3: per-row finalize — UNCHANGED except BDYN (widened for gemm1-MFMA).
// ---------------------------------------------------------------------------
__global__ __launch_bounds__(256) void finalize_rows(
    float* __restrict__ C,
    const float* __restrict__ wr1, const float* __restrict__ br1,
    const float* __restrict__ wr2, const float* __restrict__ br2,
    const float* __restrict__ wm1, const float* __restrict__ bm1,
    const float* __restrict__ wm2, const float* __restrict__ bm2,
    const int* __restrict__ corr,
    unsigned* __restrict__ rctr, unsigned* __restrict__ rowlist)
{
    const int D = 1024;
    const int tid = threadIdx.x;
    const int lane = tid & 63;
    const unsigned row = blockIdx.x * 4 + (tid >> 6);
    const size_t base = (size_t)row * D;
    const int col0 = lane * 4;

    float4 c4[4];
    #pragma unroll
    for (int q = 0; q < 4; ++q)
        c4[q] = *(const float4*)(C + base + q * 256 + col0);

    float c[16];
    #pragma unroll
    for (int q = 0; q < 4; ++q) {
        c[q * 4 + 0] = c4[q].x; c[q * 4 + 1] = c4[q].y;
        c[q * 4 + 2] = c4[q].z; c[q * 4 + 3] = c4[q].w;
    }

    float cnt = 0.f;
    #pragma unroll
    for (int i = 0; i < 16; ++i) cnt += (fabsf(c[i]) < 0.1f) ? 1.f : 0.f;
    #pragma unroll
    for (int o = 32; o > 0; o >>= 1) cnt += __shfl_xor(cnt, o, 64);
    cnt += (float)corr[row];
    const double cur_sp = (double)cnt / 1024.0;

    float hid[16];
    #pragma unroll
    for (int h = 0; h < 16; ++h) {
        double z = cur_sp * (double)wr1[h] + 0.1 * (double)wr1[16 + h] + (double)br1[h];
        hid[h] = (float)((z > 0.0) ? z : 0.0);
    }

    float dyn[16];
    #pragma unroll
    for (int q = 0; q < 4; ++q) {
        const int cq = q * 256 + col0;
        float4 b4 = *(const float4*)(br2 + cq);
        float z[4] = {b4.x, b4.y, b4.z, b4.w};
        #pragma unroll
        for (int h = 0; h < 16; ++h) {
            float4 w4 = *(const float4*)(wr2 + (size_t)h * D + cq);
            z[0] = fmaf(hid[h], w4.x, z[0]);
            z[1] = fmaf(hid[h], w4.y, z[1]);
            z[2] = fmaf(hid[h], w4.z, z[2]);
            z[3] = fmaf(hid[h], w4.w, z[3]);
        }
        #pragma unroll
        for (int j = 0; j < 4; ++j) {
            float rw = 1.0f / (1.0f + __expf(-z[j]));
            dyn[q * 4 + j] = c[q * 4 + j] * rw;
        }
    }

    float s = 0.f, mx = -1e30f;
    #pragma unroll
    for (int i = 0; i < 16; ++i) { s += dyn[i]; mx = fmaxf(mx, dyn[i]); }
    #pragma unroll
    for (int o = 32; o > 0; o >>= 1) s += __shfl_xor(s, o, 64);
    const float mean = s / 1024.0f;

    float sq = 0.f;
    #pragma unroll
    for (int i = 0; i < 16; ++i) { float d = dyn[i] - mean; sq = fmaf(d, d, sq); }
    #pragma unroll
    for (int o = 32; o > 0; o >>= 1) sq += __shfl_xor(sq, o, 64);
    const float sd = sqrtf(sq / 1023.0f);

    #pragma unroll
    for (int o = 32; o > 0; o >>= 1) mx = fmaxf(mx, __shfl_xor(mx, o, 64));

    double acc2 = (double)bm2[0];
    #pragma unroll
    for (int h = 0; h < 16; ++h) {
        double hz = (double)mean * (double)wm1[h] + (double)sd * (double)wm1[16 + h]
                  + (double)mx * (double)wm1[32 + h] + (double)bm1[h];
        hz = (hz > 0.0) ? hz : 0.0;
        acc2 += hz * (double)wm2[h];
    }
    const float thr = (float)(1.0 / (1.0 + exp(-acc2)));

    bool fl = false;
    #pragma unroll
    for (int i = 0; i < 16; ++i)
        if (fabsf(fabsf(dyn[i]) - thr) < BDYN) fl = true;

    if (__any(fl)) {
        if (lane == 0) {
            unsigned idx = atomicAdd(rctr, 1u);
            if (idx < ROWCAP) rowlist[idx] = row;
        }
        return;                         // preserve comp row for row_exact
    }

    #pragma unroll
    for (int q = 0; q < 4; ++q) {
        float4 o4;
        float* op = &o4.x;
        #pragma unroll
        for (int j = 0; j < 4; ++j) {
            float d = dyn[q * 4 + j];
            op[j] = (fabsf(d) > thr) ? d : 0.f;
        }
        *(float4*)(C + base + q * 256 + col0) = o4;
    }
}

// ---------------------------------------------------------------------------
// fp64 block reduction helper (256 threads).
// ---------------------------------------------------------------------------
__device__ __forceinline__ double block_reduce_d(double v, double* sm, int tid, int op)
{
    #pragma unroll
    for (int o = 32; o > 0; o >>= 1) {
        double other = __shfl_down(v, o, 64);
        v = op ? fmax(v, other) : (v + other);
    }
    if ((tid & 63) == 0) sm[tid >> 6] = v;
    __syncthreads();
    if (tid == 0) {
        double r = sm[0];
        for (int w = 1; w < 4; ++w) r = op ? fmax(r, sm[w]) : (r + sm[w]);
        sm[4] = r;
    }
    __syncthreads();
    double r = sm[4];
    __syncthreads();
    return r;
}

// ---------------------------------------------------------------------------
// row_exact — UNCHANGED (validated round 8; exact-from-F, immune to MFMA).
// ---------------------------------------------------------------------------
__global__ __launch_bounds__(256) void row_exact(
    const float* __restrict__ F,
    const float* __restrict__ wg1, const float* __restrict__ bg1,
    const float* __restrict__ wg2, const float* __restrict__ bg2,
    const float* __restrict__ wr1, const float* __restrict__ br1,
    const float* __restrict__ wr2, const float* __restrict__ br2,
    const float* __restrict__ wm1, const float* __restrict__ bm1,
    const float* __restrict__ wm2, const float* __restrict__ bm2,
    const unsigned* __restrict__ rctr, const unsigned* __restrict__ rowlist,
    float* __restrict__ out)
{
    __shared__ float  Fs[1024];
    __shared__ float  Wt[2][4096];   // 2 x 16KB tiles
    __shared__ double h1d[256];
    __shared__ double sm[8];
    const int tid = threadIdx.x;
    unsigned rcnt = *rctr;
    if (rcnt > ROWCAP) rcnt = ROWCAP;

    for (unsigned e = blockIdx.x; e < rcnt; e += gridDim.x) {
        const unsigned row = rowlist[e];
        __syncthreads();
        *(float4*)&Fs[tid * 4] = *(const float4*)(F + (size_t)row * 1024 + tid * 4);

        {
            float4 r0, r1, r2, r3;
            WT_PREFETCH(wg1)
            WT_STORE(0)
            __syncthreads();
            double p0 = 0.0, p1 = 0.0, p2 = 0.0, p3 = 0.0;
            int buf = 0;
            for (int t = 0; t < 64; ++t) {
                if (t + 1 < 64) { const float* np = wg1 + (size_t)(t + 1) * 4096; WT_PREFETCH(np) }
                const int kb = t * 16;
                #pragma unroll
                for (int kk = 0; kk < 16; kk += 4) {
                    p0 += (double)Fs[kb + kk + 0] * (double)Wt[buf][(kk + 0) * 256 + tid];
                    p1 += (double)Fs[kb + kk + 1] * (double)Wt[buf][(kk + 1) * 256 + tid];
                    p2 += (double)Fs[kb + kk + 2] * (double)Wt[buf][(kk + 2) * 256 + tid];
                    p3 += (double)Fs[kb + kk + 3] * (double)Wt[buf][(kk + 3) * 256 + tid];
                }
                if (t + 1 < 64) {
                    const int nb = buf ^ 1;
                    WT_STORE(nb)
                    __syncthreads();
                    buf = nb;
                }
            }
            double a = ((p0 + p1) + (p2 + p3)) + (double)bg1[tid];
            h1d[tid] = (a > 0.0) ? a : 0.0;
        }
        __syncthreads();

        const int c0 = tid * 4;
        double zA[4] = {0.0, 0.0, 0.0, 0.0};
        double zB[4] = {0.0, 0.0, 0.0, 0.0};
        {
            float4 r0, r1, r2, r3;
            WT_PREFETCH(wg2)
            WT_STORE(0)
            __syncthreads();
            int buf = 0;
            for (int t = 0; t < 64; ++t) {
                if (t + 1 < 64) { const float* np = wg2 + (size_t)(t + 1) * 4096; WT_PREFETCH(np) }
                const int jb = t * 4;
                #pragma unroll
                for (int kk = 0; kk < 4; kk += 2) {
                    float4 wA = *(const float4*)&Wt[buf][(kk + 0) * 1024 + c0];
                    float4 wB = *(const float4*)&Wt[buf][(kk + 1) * 1024 + c0];
                    double hA = h1d[jb + kk], hB = h1d[jb + kk + 1];
                    zA[0] += hA * (double)wA.x; zA[1] += hA * (double)wA.y;
                    zA[2] += hA * (double)wA.z; zA[3] += hA * (double)wA.w;
                    zB[0] += hB * (double)wB.x; zB[1] += hB * (double)wB.y;
                    zB[2] += hB * (double)wB.z; zB[3] += hB * (double)wB.w;
                }
                if (t + 1 < 64) {
                    const int nb = buf ^ 1;
                    WT_STORE(nb)
                    __syncthreads();
                    buf = nb;
                }
            }
        }
        double comp[4];
        double cnt = 0.0;
        #pragma unroll
        for (int j = 0; j < 4; ++j) {
            double z2v = (double)bg2[c0 + j] + zA[j] + zB[j];
            double gw = 1.0 / (1.0 + exp(-z2v));
            double g = (double)Fs[c0 + j] * gw;
            double cm = (g > 0.3) ? 0.0 : g;
            comp[j] = cm;
            cnt += (fabs(cm) < 0.1) ? 1.0 : 0.0;
        }
        cnt = block_reduce_d(cnt, sm, tid, 0);
        const double cur_sp = cnt / 1024.0;

        double hid[16];
        #pragma unroll
        for (int h = 0; h < 16; ++h) {
            double hz = cur_sp * (double)wr1[h] + 0.1 * (double)wr1[16 + h] + (double)br1[h];
            hid[h] = (hz > 0.0) ? hz : 0.0;
        }
        double zr[4] = {(double)br2[c0], (double)br2[c0 + 1],
                        (double)br2[c0 + 2], (double)br2[c0 + 3]};
        #pragma unroll
        for (int h = 0; h < 16; ++h) {
            float4 w4 = *(const float4*)(wr2 + (size_t)h * 1024 + c0);
            zr[0] += hid[h] * (double)w4.x; zr[1] += hid[h] * (double)w4.y;
            zr[2] += hid[h] * (double)w4.z; zr[3] += hid[h] * (double)w4.w;
        }
        double dyn[4];
        #pragma unroll
        for (int j = 0; j < 4; ++j) {
            double rw = 1.0 / (1.0 + exp(-zr[j]));
            dyn[j] = comp[j] * rw;
        }

        double s = dyn[0] + dyn[1] + dyn[2] + dyn[3];
        s = block_reduce_d(s, sm, tid, 0);
        const double mean = s / 1024.0;

        double sq = 0.0;
        #pragma unroll
        for (int j = 0; j < 4; ++j) { double d = dyn[j] - mean; sq += d * d; }
        sq = block_reduce_d(sq, sm, tid, 0);
        const double sd = sqrt(sq / 1023.0);

        double mx = fmax(fmax(dyn[0], dyn[1]), fmax(dyn[2], dyn[3]));
        mx = block_reduce_d(mx, sm, tid, 1);

        double acc2 = (double)bm2[0];
        #pragma unroll
        for (int h = 0; h < 16; ++h) {
            double hz = mean * (double)wm1[h] + sd * (double)wm1[16 + h]
                      + mx * (double)wm1[32 + h] + (double)bm1[h];
            hz = (hz > 0.0) ? hz : 0.0;
            acc2 += hz * (double)wm2[h];
        }
        const double thr = 1.0 / (1.0 + exp(-acc2));

        float4 o4;
        o4.x = (float)((fabs(dyn[0]) > thr) ? dyn[0] : 0.0);
        o4.y = (float)((fabs(dyn[1]) > thr) ? dyn[1] : 0.0);
        o4.z = (float)((fabs(dyn[2]) > thr) ? dyn[2] : 0.0);
        o4.w = (float)((fabs(dyn[3]) > thr) ? dyn[3] : 0.0);
        *(float4*)(out + (size_t)row * 1024 + c0) = o4;
    }
}

// ---------------------------------------------------------------------------
// Workspace map (max offset 36 MiB + 256 KiB + 16 B — the validated bound):
//   [0,   32M)  h1
//   [32M, 33M)  wg1Th/Tl (512K each) -- dead after gemm1_mfma; region is then
//               reused as the FRONT of elist1 [32M,34M) (written by
//               gemm2_mfma, which runs after gemm1_mfma -- stream-ordered)
//   [34M, 35M)  wg2Th/Tl -- dead after gemm2_mfma
//   [35M, 36M)  elist2 (first written by fix_near)
//   [36M, +128K) rowlist ; [+128K,+256K) corr ; [+256K,+16B) counters
// ---------------------------------------------------------------------------
extern "C" void kernel_launch(void* const* d_in, const int* in_sizes, int n_in,
                              void* d_out, int out_size, void* d_ws, size_t ws_size,
                              hipStream_t stream)
{
    const float* F   = (const float*)d_in[0];
    const float* wg1 = (const float*)d_in[1];
    const float* bg1 = (const float*)d_in[2];
    const float* wg2 = (const float*)d_in[3];
    const float* bg2 = (const float*)d_in[4];
    // d_in[5..8]: competition calculator — provably dead (win == False always)
    const float* wr1 = (const float*)d_in[9];
    const float* br1 = (const float*)d_in[10];
    const float* wr2 = (const float*)d_in[11];
    const float* br2 = (const float*)d_in[12];
    const float* wm1 = (const float*)d_in[13];
    const float* bm1 = (const float*)d_in[14];
    const float* wm2 = (const float*)d_in[15];
    const float* bm2 = (const float*)d_in[16];

    float* out = (float*)d_out;
    const int M = in_sizes[0] / 1024;                      // 32768

    char* ws = (char*)d_ws;
    float*          h1      = (float*)ws;                              // 32 MiB
    unsigned short* wg1Th   = (unsigned short*)(ws + (32u << 20));     // 512 KiB
    unsigned short* wg1Tl   = (unsigned short*)(ws + (32u << 20) + (512u << 10));
    uint2*          elist1  = (uint2*)(ws + (32u << 20));              // 2 MiB (after gemm1)
    unsigned short* wg2Th   = (unsigned short*)(ws + (34u << 20));     // 512 KiB
    unsigned short* wg2Tl   = (unsigned short*)(ws + (34u << 20) + (512u << 10));
    uint2*          elist2  = (uint2*)(ws + (35u << 20));              // 1 MiB
    unsigned*       rowlist = (unsigned*)(ws + (36u << 20));           // 128 KiB
    int*            corr    = (int*)(ws + (36u << 20) + (128u << 10)); // 128 KiB
    unsigned*       ctrs    = (unsigned*)(ws + (36u << 20) + (256u << 10));
    unsigned* ectr1 = ctrs, *ectr2 = ctrs + 1, *rctr = ctrs + 2;

    hipMemsetAsync(corr, 0, (size_t)M * sizeof(int) + 16, stream);
    split_wg1<<<256, 256, 0, stream>>>(wg1, wg1Th, wg1Tl);
    split_wg2<<<1024, 256, 0, stream>>>(wg2, wg2Th, wg2Tl);
    gemm1_mfma<<<dim3(M / 128, 256 / 128), 256, 0, stream>>>(F, wg1Th, wg1Tl, bg1, h1, M);
    gemm2_mfma<<<dim3(M / 128, 1024 / 128), 256, 0, stream>>>(h1, wg2Th, wg2Tl, bg2, F,
                                                              out, ectr1, elist1, M);
    fix_near<<<2048, 256, 0, stream>>>(h1, F, wg2, bg2, ectr1, elist1, ectr2, elist2, out, corr);
    fix_full<<<1024, 256, 0, stream>>>(F, wg1, bg1, wg2, bg2, ectr2, elist2, out, corr);
    finalize_rows<<<M / 4, 256, 0, stream>>>(out, wr1, br1, wr2, br2, wm1, bm1, wm2, bm2,
                                             corr, rctr, rowlist);
    row_exact<<<2048, 256, 0, stream>>>(F, wg1, bg1, wg2, bg2, wr1, br1, wr2, br2,
                                        wm1, bm1, wm2, bm2, rctr, rowlist, out);
}